// Round 15
// baseline (160.025 us; speedup 1.0000x reference)
//
#include <hip/hip_runtime.h>
#include <hip/hip_fp16.h>

#define Nn    50000
#define Ee    800000
#define IND   128
#define HIDD  64
#define OUTD  32
#define NBUCK ((Nn + 255) / 256)        // 196 buckets of 256 nodes
#define EPB   4096                      // edges per bin block
#define NBB   ((Ee + EPB - 1) / EPB)    // 196 bin blocks
#define SCAP  6144                      // staged capacity per bucket
#define RB    64                        // gemm1 rows per block
#define GB    ((Nn + RB - 1) / RB)      // 782
#define XSTR  136                       // padded half-stride (2-way LDS conflicts only)

typedef _Float16 f16x8 __attribute__((ext_vector_type(8)));
typedef float    f32x4 __attribute__((ext_vector_type(4)));

__device__ __forceinline__ int ld_nt_i32(const int* p) {
    return __builtin_nontemporal_load(p);
}
__device__ __forceinline__ long long ld_nt_i64(const long long* p) {
    return __builtin_nontemporal_load(p);
}

// accumulate 8 halves (as uint4) into 8 fp32
__device__ __forceinline__ void acc8(float* a, uint4 v) {
    float2 f0 = __half22float2(*(__half2*)&v.x);
    float2 f1 = __half22float2(*(__half2*)&v.y);
    float2 f2 = __half22float2(*(__half2*)&v.z);
    float2 f3 = __half22float2(*(__half2*)&v.w);
    a[0] += f0.x; a[1] += f0.y; a[2] += f1.x; a[3] += f1.y;
    a[4] += f2.x; a[5] += f2.y; a[6] += f3.x; a[7] += f3.y;
}

// ---- prep: zero gcur + build padded fp16 W1^T (WTg[n*136+k]) ----
__global__ void k_prep(const float* __restrict__ W, int* __restrict__ gcur,
                       _Float16* __restrict__ WTg) {
    int t = threadIdx.x;
    if (t < NBUCK) gcur[t] = 0;
    for (int j = 0; j < 32; ++j) {
        int idx = j * 256 + t;             // coalesced read of W
        int k = idx >> 6, n = idx & 63;
        WTg[n * XSTR + k] = (_Float16)W[idx];
    }
}

// ---- fused: bucket-bin (blocks [0,NBB)) + MFMA GEMM1 (blocks [NBB,NBB+GB)) ----
__global__ __launch_bounds__(256) void k_bin_gemm1(const void* __restrict__ p,
        int* __restrict__ gcur, unsigned int* __restrict__ staged,
        const float* __restrict__ x, const _Float16* __restrict__ WTg,
        __half* __restrict__ h1raw) {
    __shared__ alignas(16) char smem[21504];
    int t = threadIdx.x;
    if (blockIdx.x < NBB) {
        unsigned int* stage = (unsigned int*)smem;          // 16 KB
        int* hist  = (int*)(smem + 16384);
        int* offs  = hist + 256;
        int* lcur  = offs + 256;
        int* gposs = lcur + 256;
        unsigned int* red = (unsigned int*)(gposs + 256);
        int base0 = blockIdx.x * EPB;
        red[t] = ((const unsigned int*)p)[2 * (base0 + t) + 1];
        hist[t] = 0;
        __syncthreads();
        for (int s = 128; s > 0; s >>= 1) {
            if (t < s) red[t] |= red[t + s];
            __syncthreads();
        }
        bool f64 = (red[0] == 0u);
        int nv = Ee - base0; if (nv > EPB) nv = EPB;
        unsigned int pl[16];
        #pragma unroll
        for (int q = 0; q < 16; ++q) {
            int e = base0 + q * 256 + t;
            if (e < Ee) {
                int r, c;
                if (f64) { r = (int)ld_nt_i64((const long long*)p + e);
                           c = (int)ld_nt_i64((const long long*)p + Ee + e); }
                else     { r = ld_nt_i32((const int*)p + e);
                           c = ld_nt_i32((const int*)p + Ee + e); }
                pl[q] = ((unsigned int)c << 16) | (unsigned int)r;
                atomicAdd(&hist[pl[q] >> 24], 1);
            }
        }
        __syncthreads();
        int v = hist[t];
        offs[t] = v;
        __syncthreads();
        for (int off = 1; off < 256; off <<= 1) {
            int add = (t >= off) ? offs[t - off] : 0;
            __syncthreads();
            offs[t] += add;
            __syncthreads();
        }
        int excl = offs[t] - v;
        __syncthreads();
        offs[t] = excl;
        lcur[t] = excl;
        __syncthreads();
        #pragma unroll
        for (int q = 0; q < 16; ++q) {
            int e = base0 + q * 256 + t;
            if (e < Ee) {
                int bk = pl[q] >> 24;
                int pos = atomicAdd(&lcur[bk], 1);
                stage[pos] = pl[q];
            }
        }
        if (t < NBUCK) {
            int hh = hist[t];
            gposs[t] = hh ? atomicAdd(&gcur[t], hh) : 0;
        }
        __syncthreads();
        for (int i = t; i < nv; i += 256) {
            unsigned int pv = stage[i];
            int bk = pv >> 24;
            int idx = gposs[bk] + (i - offs[bk]);
            if (idx < SCAP) staged[(size_t)bk * SCAP + idx] = pv;
        }
        return;
    }
    // gemm1 (MFMA 16x16x32 f16): h1raw = x @ W1
    _Float16* Xl = (_Float16*)smem;     // 64 x 136 halves, 17.4 KB
    int bid = blockIdx.x - NBB;
    int row0 = bid * RB;
    for (int i = t; i < RB * (IND / 4); i += 256) {
        int rr = i >> 5, kk = (i & 31) * 4;
        int gr = row0 + rr;
        float4 v = make_float4(0.f, 0.f, 0.f, 0.f);
        if (gr < Nn) v = ((const float4*)x)[(size_t)gr * (IND / 4) + (i & 31)];
        _Float16* dst = &Xl[rr * XSTR + kk];
        dst[0] = (_Float16)v.x; dst[1] = (_Float16)v.y;
        dst[2] = (_Float16)v.z; dst[3] = (_Float16)v.w;
    }
    __syncthreads();
    int wv = t >> 6, lane = t & 63;
    int m = lane & 15, quad = lane >> 4;
    f32x4 acc[4] = {{0.f,0.f,0.f,0.f},{0.f,0.f,0.f,0.f},
                    {0.f,0.f,0.f,0.f},{0.f,0.f,0.f,0.f}};
    const _Float16* xrow = &Xl[(wv * 16 + m) * XSTR + quad * 8];
    #pragma unroll
    for (int kt = 0; kt < 4; ++kt) {
        f16x8 av = *(const f16x8*)(xrow + kt * 32);
        #pragma unroll
        for (int ct = 0; ct < 4; ++ct) {
            f16x8 bv = *(const f16x8*)&WTg[(ct * 16 + m) * XSTR + kt * 32 + quad * 8];
            acc[ct] = __builtin_amdgcn_mfma_f32_16x16x32_f16(av, bv, acc[ct], 0, 0, 0);
        }
    }
    int rbase = row0 + wv * 16 + quad * 4;
    #pragma unroll
    for (int reg = 0; reg < 4; ++reg) {
        int gr = rbase + reg;
        if (gr < Nn) {
            #pragma unroll
            for (int ct = 0; ct < 4; ++ct)
                h1raw[(size_t)gr * HIDD + ct * 16 + m] = __float2half(acc[ct][reg]);
        }
    }
}

// ---- pass 2: per-bucket hist+scan+sort -> rowstart, dis, slots; + scale h1 ----
__global__ __launch_bounds__(256) void k_bsort(const unsigned int* __restrict__ staged,
        const int* __restrict__ gcur, int* __restrict__ rowstart,
        float* __restrict__ dis, unsigned short* __restrict__ slots,
        __half2* __restrict__ h1v) {
    __shared__ int bsc[256];
    __shared__ int hist[256], nodestart[256], cur[256];
    __shared__ float ndis[256];
    __shared__ unsigned short sortbuf[SCAP];   // 12 KB
    int t = threadIdx.x, b = blockIdx.x;
    int gv = (t < NBUCK) ? min(gcur[t], SCAP) : 0;
    bsc[t] = gv;
    hist[t] = 0;
    __syncthreads();
    for (int off = 1; off < 256; off <<= 1) {
        int add = (t >= off) ? bsc[t - off] : 0;
        __syncthreads();
        bsc[t] += add;
        __syncthreads();
    }
    int bucketbase = (b == 0) ? 0 : bsc[b - 1];
    int m = bsc[b] - bucketbase;
    const unsigned int* sp = staged + (size_t)b * SCAP;
    for (int i = t; i < m; i += 256) atomicAdd(&hist[(sp[i] >> 16) & 255], 1);
    __syncthreads();
    int v = hist[t];
    nodestart[t] = v;
    __syncthreads();
    for (int off = 1; off < 256; off <<= 1) {
        int add = (t >= off) ? nodestart[t - off] : 0;
        __syncthreads();
        nodestart[t] += add;
        __syncthreads();
    }
    int excl = nodestart[t] - v;
    __syncthreads();
    nodestart[t] = excl;
    cur[t] = 0;
    int node = b * 256 + t;
    float dd = rsqrtf((float)v + 1.0f);
    ndis[t] = dd;
    if (node < Nn) {
        rowstart[node] = bucketbase + excl;
        dis[node] = dd;
    }
    if (b == NBUCK - 1 && t == 0) rowstart[Nn] = Ee;
    __syncthreads();
    for (int i = t; i < m; i += 256) {
        unsigned int pv = sp[i];
        int lc = (pv >> 16) & 255;
        int pos = nodestart[lc] + atomicAdd(&cur[lc], 1);
        sortbuf[pos] = (unsigned short)(pv & 0xFFFFu);
    }
    __syncthreads();
    for (int i = t; i < m; i += 256) slots[bucketbase + i] = sortbuf[i];
    // scale this bucket's h1 rows in place: g1 = dis * h1raw (coalesced)
    for (int i = t; i < 256 * 32; i += 256) {
        int nl = i >> 5;
        int n = b * 256 + nl;
        if (n < Nn) {
            float2 f = __half22float2(h1v[(size_t)n * 32 + (i & 31)]);
            float d = ndis[nl];
            h1v[(size_t)n * 32 + (i & 31)] = __floats2half2_rn(d * f.x, d * f.y);
        }
    }
}

// ---- layer-1 agg + fused GEMM2: 32 nodes/block, 8 lanes/node x 16B ----
// masked full-width batches: every node finishes in ceil(deg/16) (+1) rounds
__global__ __launch_bounds__(256) void k_agg1(const unsigned short* __restrict__ slots,
        const int* __restrict__ rowstart, const float* __restrict__ dis,
        const uint4* __restrict__ h1q, const float* __restrict__ b1,
        const float* __restrict__ W2, __half* __restrict__ h2) {
    __shared__ float sh[32 * 65];      // stride 65: conflict-free gemm2 reads, 8.3 KB
    __shared__ float W2s[HIDD * OUTD]; // 8 KB
    int t = threadIdx.x;
    for (int i = t; i < HIDD * OUTD; i += 256) W2s[i] = W2[i];
    int sub = t >> 3, lane = t & 7;    // 8 lanes/node, 16 B each
    int n = blockIdx.x * 32 + sub;
    if (n < Nn) {
        int s = rowstart[n], e = rowstart[n + 1];
        float d = dis[n];
        float acc[8] = {0,0,0,0,0,0,0,0};
        int p = s;
        for (; p + 8 < e; p += 16) {          // masked 16-batch while >8 remain
            int rv[16];
            #pragma unroll
            for (int q = 0; q < 16; ++q) {
                int idx = p + q;
                rv[q] = slots[idx < e ? idx : e - 1];
            }
            uint4 fv[16];
            #pragma unroll
            for (int q = 0; q < 16; ++q) fv[q] = h1q[rv[q] * 8 + lane];
            #pragma unroll
            for (int q = 0; q < 16; ++q)
                if (p + q < e) acc8(acc, fv[q]);
        }
        if (p < e) {                          // masked 8-batch tail
            int rv[8];
            #pragma unroll
            for (int q = 0; q < 8; ++q) {
                int idx = p + q;
                rv[q] = slots[idx < e ? idx : e - 1];
            }
            uint4 fv[8];
            #pragma unroll
            for (int q = 0; q < 8; ++q) fv[q] = h1q[rv[q] * 8 + lane];
            #pragma unroll
            for (int q = 0; q < 8; ++q)
                if (p + q < e) acc8(acc, fv[q]);
        }
        acc8(acc, h1q[n * 8 + lane]);                 // self (g1 includes dis)
        #pragma unroll
        for (int j = 0; j < 8; ++j)
            sh[sub * 65 + lane * 8 + j] = fmaxf(b1[lane * 8 + j] + d * acc[j], 0.0f);
    }
    __syncthreads();
    // gemm2: thread t -> node t>>3, outputs (t&7)*4..+3
    int nl = t >> 3, j0 = (t & 7) * 4;
    float o[4] = {0, 0, 0, 0};
    #pragma unroll
    for (int k = 0; k < HIDD; ++k) {
        float sv = sh[nl * 65 + k];
        float4 w4 = *(const float4*)&W2s[k * OUTD + j0];
        o[0] = fmaf(sv, w4.x, o[0]); o[1] = fmaf(sv, w4.y, o[1]);
        o[2] = fmaf(sv, w4.z, o[2]); o[3] = fmaf(sv, w4.w, o[3]);
    }
    int n2 = blockIdx.x * 32 + nl;
    if (n2 < Nn) {
        float d2 = dis[n2];
        __half hv[4];
        #pragma unroll
        for (int q = 0; q < 4; ++q) hv[q] = __float2half(d2 * o[q]);
        *(uint2*)&h2[(size_t)n2 * OUTD + j0] = *(uint2*)hv;   // g2 = dis * h2raw
    }
}

// ---- layer-2 agg: 64 nodes/block, 4 lanes/node x 16B, masked batches ----
__global__ __launch_bounds__(256) void k_agg2(const unsigned short* __restrict__ slots,
        const int* __restrict__ rowstart, const float* __restrict__ dis,
        const uint4* __restrict__ h2q, const float* __restrict__ b2,
        float* __restrict__ out) {
    int t = threadIdx.x;
    int sub = t >> 2, lane = t & 3;    // 4 lanes/node, 16 B each
    int n = blockIdx.x * 64 + sub;
    if (n >= Nn) return;
    int s = rowstart[n], e = rowstart[n + 1];
    float d = dis[n];
    float acc[8] = {0,0,0,0,0,0,0,0};
    int p = s;
    for (; p + 8 < e; p += 16) {
        int rv[16];
        #pragma unroll
        for (int q = 0; q < 16; ++q) {
            int idx = p + q;
            rv[q] = slots[idx < e ? idx : e - 1];
        }
        uint4 fv[16];
        #pragma unroll
        for (int q = 0; q < 16; ++q) fv[q] = h2q[rv[q] * 4 + lane];
        #pragma unroll
        for (int q = 0; q < 16; ++q)
            if (p + q < e) acc8(acc, fv[q]);
    }
    if (p < e) {
        int rv[8];
        #pragma unroll
        for (int q = 0; q < 8; ++q) {
            int idx = p + q;
            rv[q] = slots[idx < e ? idx : e - 1];
        }
        uint4 fv[8];
        #pragma unroll
        for (int q = 0; q < 8; ++q) fv[q] = h2q[rv[q] * 4 + lane];
        #pragma unroll
        for (int q = 0; q < 8; ++q)
            if (p + q < e) acc8(acc, fv[q]);
    }
    acc8(acc, h2q[n * 4 + lane]);                    // self
    float4 r0, r1;
    r0.x = b2[lane * 8 + 0] + d * acc[0]; r0.y = b2[lane * 8 + 1] + d * acc[1];
    r0.z = b2[lane * 8 + 2] + d * acc[2]; r0.w = b2[lane * 8 + 3] + d * acc[3];
    r1.x = b2[lane * 8 + 4] + d * acc[4]; r1.y = b2[lane * 8 + 5] + d * acc[5];
    r1.z = b2[lane * 8 + 6] + d * acc[6]; r1.w = b2[lane * 8 + 7] + d * acc[7];
    float4* op = (float4*)&out[(size_t)n * OUTD + lane * 8];
    op[0] = r0; op[1] = r1;
}

extern "C" void kernel_launch(void* const* d_in, const int* in_sizes, int n_in,
                              void* d_out, int out_size, void* d_ws, size_t ws_size,
                              hipStream_t stream) {
    const float* x  = (const float*)d_in[0];
    const void*  ei = d_in[1];
    const float* W1 = (const float*)d_in[2];
    const float* b1 = (const float*)d_in[3];
    const float* W2 = (const float*)d_in[4];
    const float* b2 = (const float*)d_in[5];
    float* out = (float*)d_out;

    char* w = (char*)d_ws;
    int*            gcur     = (int*)w;            w += ((size_t)NBUCK * 4 + 255) / 256 * 256;
    int*            rowstart = (int*)w;            w += (size_t)(Nn + 1) * 4 + 188;
    float*          dis      = (float*)w;          w += (size_t)Nn * 4;
    _Float16*       WTg      = (_Float16*)w;       w += 64 * XSTR * 2 + 128;      // 17.5 KB
    unsigned int*   staged   = (unsigned int*)w;   w += (size_t)NBUCK * SCAP * 4; // 4.8 MB
    unsigned short* slots    = (unsigned short*)w; w += (size_t)Ee * 2;           // 1.6 MB
    __half*         h1       = (__half*)w;         w += (size_t)Nn * HIDD * 2;    // 6.4 MB
    __half*         h2       = (__half*)w;         w += (size_t)Nn * OUTD * 2;    // 3.2 MB

    k_prep     <<<1, 256, 0, stream>>>(W1, gcur, WTg);
    k_bin_gemm1<<<NBB + GB, 256, 0, stream>>>(ei, gcur, staged, x, WTg, h1);
    k_bsort    <<<NBUCK, 256, 0, stream>>>(staged, gcur, rowstart, dis, slots,
                                           (__half2*)h1);
    k_agg1     <<<(Nn + 31) / 32, 256, 0, stream>>>(slots, rowstart, dis,
                                                    (const uint4*)h1, b1, W2, h2);
    k_agg2     <<<(Nn + 63) / 64, 256, 0, stream>>>(slots, rowstart, dis,
                                                    (const uint4*)h2, b2, out);
}

// Round 16
// 156.656 us; speedup vs baseline: 1.0215x; 1.0215x over previous
//
#include <hip/hip_runtime.h>
#include <hip/hip_fp16.h>

#define Nn    50000
#define Ee    800000
#define IND   128
#define HIDD  64
#define OUTD  32
#define NBUCK ((Nn + 255) / 256)        // 196 buckets of 256 nodes
#define EPB   4096                      // edges per bin block
#define NBB   ((Ee + EPB - 1) / EPB)    // 196 bin blocks
#define SCAP  6144                      // staged capacity per bucket
#define RB    64                        // gemm1 rows per block
#define GB    ((Nn + RB - 1) / RB)      // 782
#define XSTR  136                       // padded half-stride W1^T
#define W2STR 72                        // padded half-stride W2^T

typedef _Float16 f16x8 __attribute__((ext_vector_type(8)));
typedef float    f32x4 __attribute__((ext_vector_type(4)));

__device__ __forceinline__ int ld_nt_i32(const int* p) {
    return __builtin_nontemporal_load(p);
}
__device__ __forceinline__ long long ld_nt_i64(const long long* p) {
    return __builtin_nontemporal_load(p);
}

// accumulate 8 halves (as uint4) into 8 fp32
__device__ __forceinline__ void acc8(float* a, uint4 v) {
    float2 f0 = __half22float2(*(__half2*)&v.x);
    float2 f1 = __half22float2(*(__half2*)&v.y);
    float2 f2 = __half22float2(*(__half2*)&v.z);
    float2 f3 = __half22float2(*(__half2*)&v.w);
    a[0] += f0.x; a[1] += f0.y; a[2] += f1.x; a[3] += f1.y;
    a[4] += f2.x; a[5] += f2.y; a[6] += f3.x; a[7] += f3.y;
}

// ---- prep (17 blocks): b0 zeroes gcur + builds W2^T; b1..16 build W1^T ----
__global__ void k_prep(const float* __restrict__ W1, const float* __restrict__ W2,
                       int* __restrict__ gcur, _Float16* __restrict__ WTg,
                       _Float16* __restrict__ W2T) {
    int t = threadIdx.x, b = blockIdx.x;
    if (b == 0) {
        if (t < NBUCK) gcur[t] = 0;
        for (int j = 0; j < 8; ++j) {
            int idx = j * 256 + t;                 // 2048 = 64x32
            int k = idx >> 5, n = idx & 31;
            W2T[n * W2STR + k] = (_Float16)W2[idx];
        }
        return;
    }
    int base = (b - 1) * 512;
    #pragma unroll
    for (int j = 0; j < 2; ++j) {
        int idx = base + j * 256 + t;              // 8192 = 128x64
        int k = idx >> 6, n = idx & 63;
        WTg[n * XSTR + k] = (_Float16)W1[idx];
    }
}

// ---- fused: bucket-bin (blocks [0,NBB)) + MFMA GEMM1 (blocks [NBB,NBB+GB)) ----
__global__ __launch_bounds__(256) void k_bin_gemm1(const void* __restrict__ p,
        int* __restrict__ gcur, unsigned int* __restrict__ staged,
        const float* __restrict__ x, const _Float16* __restrict__ WTg,
        __half* __restrict__ h1raw) {
    __shared__ alignas(16) char smem[21504];
    int t = threadIdx.x;
    if (blockIdx.x < NBB) {
        unsigned int* stage = (unsigned int*)smem;          // 16 KB
        int* hist  = (int*)(smem + 16384);
        int* offs  = hist + 256;
        int* lcur  = offs + 256;
        int* gposs = lcur + 256;
        unsigned int* red = (unsigned int*)(gposs + 256);
        int base0 = blockIdx.x * EPB;
        red[t] = ((const unsigned int*)p)[2 * (base0 + t) + 1];
        hist[t] = 0;
        __syncthreads();
        for (int s = 128; s > 0; s >>= 1) {
            if (t < s) red[t] |= red[t + s];
            __syncthreads();
        }
        bool f64 = (red[0] == 0u);
        int nv = Ee - base0; if (nv > EPB) nv = EPB;
        unsigned int pl[16];
        #pragma unroll
        for (int q = 0; q < 16; ++q) {
            int e = base0 + q * 256 + t;
            if (e < Ee) {
                int r, c;
                if (f64) { r = (int)ld_nt_i64((const long long*)p + e);
                           c = (int)ld_nt_i64((const long long*)p + Ee + e); }
                else     { r = ld_nt_i32((const int*)p + e);
                           c = ld_nt_i32((const int*)p + Ee + e); }
                pl[q] = ((unsigned int)c << 16) | (unsigned int)r;
                atomicAdd(&hist[pl[q] >> 24], 1);
            }
        }
        __syncthreads();
        int v = hist[t];
        offs[t] = v;
        __syncthreads();
        for (int off = 1; off < 256; off <<= 1) {
            int add = (t >= off) ? offs[t - off] : 0;
            __syncthreads();
            offs[t] += add;
            __syncthreads();
        }
        int excl = offs[t] - v;
        __syncthreads();
        offs[t] = excl;
        lcur[t] = excl;
        __syncthreads();
        #pragma unroll
        for (int q = 0; q < 16; ++q) {
            int e = base0 + q * 256 + t;
            if (e < Ee) {
                int bk = pl[q] >> 24;
                int pos = atomicAdd(&lcur[bk], 1);
                stage[pos] = pl[q];
            }
        }
        if (t < NBUCK) {
            int hh = hist[t];
            gposs[t] = hh ? atomicAdd(&gcur[t], hh) : 0;
        }
        __syncthreads();
        for (int i = t; i < nv; i += 256) {
            unsigned int pv = stage[i];
            int bk = pv >> 24;
            int idx = gposs[bk] + (i - offs[bk]);
            if (idx < SCAP) staged[(size_t)bk * SCAP + idx] = pv;
        }
        return;
    }
    // gemm1 (MFMA 16x16x32 f16): h1raw = x @ W1
    _Float16* Xl = (_Float16*)smem;     // 64 x 136 halves, 17.4 KB
    int bid = blockIdx.x - NBB;
    int row0 = bid * RB;
    for (int i = t; i < RB * (IND / 4); i += 256) {
        int rr = i >> 5, kk = (i & 31) * 4;
        int gr = row0 + rr;
        float4 v = make_float4(0.f, 0.f, 0.f, 0.f);
        if (gr < Nn) v = ((const float4*)x)[(size_t)gr * (IND / 4) + (i & 31)];
        _Float16* dst = &Xl[rr * XSTR + kk];
        dst[0] = (_Float16)v.x; dst[1] = (_Float16)v.y;
        dst[2] = (_Float16)v.z; dst[3] = (_Float16)v.w;
    }
    __syncthreads();
    int wv = t >> 6, lane = t & 63;
    int m = lane & 15, quad = lane >> 4;
    f32x4 acc[4] = {{0.f,0.f,0.f,0.f},{0.f,0.f,0.f,0.f},
                    {0.f,0.f,0.f,0.f},{0.f,0.f,0.f,0.f}};
    const _Float16* xrow = &Xl[(wv * 16 + m) * XSTR + quad * 8];
    #pragma unroll
    for (int kt = 0; kt < 4; ++kt) {
        f16x8 av = *(const f16x8*)(xrow + kt * 32);
        #pragma unroll
        for (int ct = 0; ct < 4; ++ct) {
            f16x8 bv = *(const f16x8*)&WTg[(ct * 16 + m) * XSTR + kt * 32 + quad * 8];
            acc[ct] = __builtin_amdgcn_mfma_f32_16x16x32_f16(av, bv, acc[ct], 0, 0, 0);
        }
    }
    int rbase = row0 + wv * 16 + quad * 4;
    #pragma unroll
    for (int reg = 0; reg < 4; ++reg) {
        int gr = rbase + reg;
        if (gr < Nn) {
            #pragma unroll
            for (int ct = 0; ct < 4; ++ct)
                h1raw[(size_t)gr * HIDD + ct * 16 + m] = __float2half(acc[ct][reg]);
        }
    }
}

// ---- pass 2: per-bucket hist+scan+sort -> rowstart, dis, slots; + scale h1 ----
__global__ __launch_bounds__(256) void k_bsort(const unsigned int* __restrict__ staged,
        const int* __restrict__ gcur, int* __restrict__ rowstart,
        float* __restrict__ dis, unsigned short* __restrict__ slots,
        __half2* __restrict__ h1v) {
    __shared__ int bsc[256];
    __shared__ int hist[256], nodestart[256], cur[256];
    __shared__ float ndis[256];
    __shared__ unsigned short sortbuf[SCAP];   // 12 KB
    int t = threadIdx.x, b = blockIdx.x;
    int gv = (t < NBUCK) ? min(gcur[t], SCAP) : 0;
    bsc[t] = gv;
    hist[t] = 0;
    __syncthreads();
    for (int off = 1; off < 256; off <<= 1) {
        int add = (t >= off) ? bsc[t - off] : 0;
        __syncthreads();
        bsc[t] += add;
        __syncthreads();
    }
    int bucketbase = (b == 0) ? 0 : bsc[b - 1];
    int m = bsc[b] - bucketbase;
    const unsigned int* sp = staged + (size_t)b * SCAP;
    for (int i = t; i < m; i += 256) atomicAdd(&hist[(sp[i] >> 16) & 255], 1);
    __syncthreads();
    int v = hist[t];
    nodestart[t] = v;
    __syncthreads();
    for (int off = 1; off < 256; off <<= 1) {
        int add = (t >= off) ? nodestart[t - off] : 0;
        __syncthreads();
        nodestart[t] += add;
        __syncthreads();
    }
    int excl = nodestart[t] - v;
    __syncthreads();
    nodestart[t] = excl;
    cur[t] = 0;
    int node = b * 256 + t;
    float dd = rsqrtf((float)v + 1.0f);
    ndis[t] = dd;
    if (node < Nn) {
        rowstart[node] = bucketbase + excl;
        dis[node] = dd;
    }
    if (b == NBUCK - 1 && t == 0) rowstart[Nn] = Ee;
    __syncthreads();
    for (int i = t; i < m; i += 256) {
        unsigned int pv = sp[i];
        int lc = (pv >> 16) & 255;
        int pos = nodestart[lc] + atomicAdd(&cur[lc], 1);
        sortbuf[pos] = (unsigned short)(pv & 0xFFFFu);
    }
    __syncthreads();
    for (int i = t; i < m; i += 256) slots[bucketbase + i] = sortbuf[i];
    // scale this bucket's h1 rows in place: g1 = dis * h1raw (coalesced)
    for (int i = t; i < 256 * 32; i += 256) {
        int nl = i >> 5;
        int n = b * 256 + nl;
        if (n < Nn) {
            float2 f = __half22float2(h1v[(size_t)n * 32 + (i & 31)]);
            float d = ndis[nl];
            h1v[(size_t)n * 32 + (i & 31)] = __floats2half2_rn(d * f.x, d * f.y);
        }
    }
}

// ---- layer-1 agg, feature-split: 64 nodes x half-row (64B) per block ----
// half = blockIdx&1 -> even/odd XCDs cache disjoint 3.2MB halves of h1 (L2-resident)
__global__ __launch_bounds__(256) void k_agg1(const unsigned short* __restrict__ slots,
        const int* __restrict__ rowstart, const float* __restrict__ dis,
        const uint4* __restrict__ h1q, const float* __restrict__ b1,
        __half* __restrict__ a1) {
    int t = threadIdx.x;
    int f = blockIdx.x & 1;            // feature half
    int g = blockIdx.x >> 1;           // node group
    int sub = t >> 2, lane = t & 3;    // 4 lanes/node, 16 B each
    int n = g * 64 + sub;
    if (n >= Nn) return;
    int s = rowstart[n], e = rowstart[n + 1];
    float d = dis[n];
    int fo = f * 4;                    // uint4 offset within row
    float acc[8] = {0,0,0,0,0,0,0,0};
    int p = s;
    for (; p + 8 < e; p += 16) {       // masked 16-batch while >8 remain
        int rv[16];
        #pragma unroll
        for (int q = 0; q < 16; ++q) {
            int idx = p + q;
            rv[q] = slots[idx < e ? idx : e - 1];
        }
        uint4 fv[16];
        #pragma unroll
        for (int q = 0; q < 16; ++q) fv[q] = h1q[rv[q] * 8 + fo + lane];
        #pragma unroll
        for (int q = 0; q < 16; ++q)
            if (p + q < e) acc8(acc, fv[q]);
    }
    if (p < e) {                       // masked 8-batch tail
        int rv[8];
        #pragma unroll
        for (int q = 0; q < 8; ++q) {
            int idx = p + q;
            rv[q] = slots[idx < e ? idx : e - 1];
        }
        uint4 fv[8];
        #pragma unroll
        for (int q = 0; q < 8; ++q) fv[q] = h1q[rv[q] * 8 + fo + lane];
        #pragma unroll
        for (int q = 0; q < 8; ++q)
            if (p + q < e) acc8(acc, fv[q]);
    }
    acc8(acc, h1q[n * 8 + fo + lane]);              // self (g1 includes dis)
    const float* bb = b1 + f * 32 + lane * 8;
    __half hv[8];
    #pragma unroll
    for (int j = 0; j < 8; ++j)
        hv[j] = __float2half(fmaxf(bb[j] + d * acc[j], 0.0f));
    *(uint4*)&a1[(size_t)n * HIDD + f * 32 + lane * 8] = *(uint4*)hv;  // full 64B line
}

// ---- GEMM2 via MFMA: h2g = dis * (a1 @ W2), 64 rows/block, no LDS ----
__global__ __launch_bounds__(256) void k_gemm2(const __half* __restrict__ a1,
        const _Float16* __restrict__ W2T, const float* __restrict__ dis,
        __half* __restrict__ h2g) {
    int t = threadIdx.x;
    int wv = t >> 6, lane = t & 63;
    int m = lane & 15, quad = lane >> 4;
    int row0 = blockIdx.x * 64 + wv * 16;
    int ar = row0 + m; if (ar > Nn - 1) ar = Nn - 1;
    const _Float16* arow = (const _Float16*)a1 + (size_t)ar * HIDD + quad * 8;
    f32x4 acc[2] = {{0.f,0.f,0.f,0.f},{0.f,0.f,0.f,0.f}};
    #pragma unroll
    for (int kt = 0; kt < 2; ++kt) {
        f16x8 av = *(const f16x8*)(arow + kt * 32);
        #pragma unroll
        for (int ct = 0; ct < 2; ++ct) {
            f16x8 bv = *(const f16x8*)&W2T[(ct * 16 + m) * W2STR + kt * 32 + quad * 8];
            acc[ct] = __builtin_amdgcn_mfma_f32_16x16x32_f16(av, bv, acc[ct], 0, 0, 0);
        }
    }
    int rbase = row0 + quad * 4;
    #pragma unroll
    for (int reg = 0; reg < 4; ++reg) {
        int gr = rbase + reg;
        if (gr < Nn) {
            float d = dis[gr];
            #pragma unroll
            for (int ct = 0; ct < 2; ++ct)
                h2g[(size_t)gr * OUTD + ct * 16 + m] = __float2half(d * acc[ct][reg]);
        }
    }
}

// ---- layer-2 agg: 64 nodes/block, 4 lanes/node x 16B, masked batches ----
__global__ __launch_bounds__(256) void k_agg2(const unsigned short* __restrict__ slots,
        const int* __restrict__ rowstart, const float* __restrict__ dis,
        const uint4* __restrict__ h2q, const float* __restrict__ b2,
        float* __restrict__ out) {
    int t = threadIdx.x;
    int sub = t >> 2, lane = t & 3;    // 4 lanes/node, 16 B each
    int n = blockIdx.x * 64 + sub;
    if (n >= Nn) return;
    int s = rowstart[n], e = rowstart[n + 1];
    float d = dis[n];
    float acc[8] = {0,0,0,0,0,0,0,0};
    int p = s;
    for (; p + 8 < e; p += 16) {
        int rv[16];
        #pragma unroll
        for (int q = 0; q < 16; ++q) {
            int idx = p + q;
            rv[q] = slots[idx < e ? idx : e - 1];
        }
        uint4 fv[16];
        #pragma unroll
        for (int q = 0; q < 16; ++q) fv[q] = h2q[rv[q] * 4 + lane];
        #pragma unroll
        for (int q = 0; q < 16; ++q)
            if (p + q < e) acc8(acc, fv[q]);
    }
    if (p < e) {
        int rv[8];
        #pragma unroll
        for (int q = 0; q < 8; ++q) {
            int idx = p + q;
            rv[q] = slots[idx < e ? idx : e - 1];
        }
        uint4 fv[8];
        #pragma unroll
        for (int q = 0; q < 8; ++q) fv[q] = h2q[rv[q] * 4 + lane];
        #pragma unroll
        for (int q = 0; q < 8; ++q)
            if (p + q < e) acc8(acc, fv[q]);
    }
    acc8(acc, h2q[n * 4 + lane]);                    // self
    float4 r0, r1;
    r0.x = b2[lane * 8 + 0] + d * acc[0]; r0.y = b2[lane * 8 + 1] + d * acc[1];
    r0.z = b2[lane * 8 + 2] + d * acc[2]; r0.w = b2[lane * 8 + 3] + d * acc[3];
    r1.x = b2[lane * 8 + 4] + d * acc[4]; r1.y = b2[lane * 8 + 5] + d * acc[5];
    r1.z = b2[lane * 8 + 6] + d * acc[6]; r1.w = b2[lane * 8 + 7] + d * acc[7];
    float4* op = (float4*)&out[(size_t)n * OUTD + lane * 8];
    op[0] = r0; op[1] = r1;
}

extern "C" void kernel_launch(void* const* d_in, const int* in_sizes, int n_in,
                              void* d_out, int out_size, void* d_ws, size_t ws_size,
                              hipStream_t stream) {
    const float* x  = (const float*)d_in[0];
    const void*  ei = d_in[1];
    const float* W1 = (const float*)d_in[2];
    const float* b1 = (const float*)d_in[3];
    const float* W2 = (const float*)d_in[4];
    const float* b2 = (const float*)d_in[5];
    float* out = (float*)d_out;

    char* w = (char*)d_ws;
    int*            gcur     = (int*)w;            w += ((size_t)NBUCK * 4 + 255) / 256 * 256;
    int*            rowstart = (int*)w;            w += (size_t)(Nn + 1) * 4 + 188;
    float*          dis      = (float*)w;          w += (size_t)Nn * 4;
    _Float16*       WTg      = (_Float16*)w;       w += 64 * XSTR * 2 + 128;      // 17.5 KB
    _Float16*       W2T      = (_Float16*)w;       w += 32 * W2STR * 2 + 128;     // 4.7 KB
    unsigned int*   staged   = (unsigned int*)w;   w += (size_t)NBUCK * SCAP * 4; // 4.8 MB
    unsigned short* slots    = (unsigned short*)w; w += (size_t)Ee * 2;           // 1.6 MB
    __half*         h1       = (__half*)w;         w += (size_t)Nn * HIDD * 2;    // 6.4 MB
    __half*         a1       = (__half*)w;         w += (size_t)Nn * HIDD * 2;    // 6.4 MB
    __half*         h2g      = (__half*)w;         w += (size_t)Nn * OUTD * 2;    // 3.2 MB

    k_prep     <<<17, 256, 0, stream>>>(W1, W2, gcur, WTg, W2T);
    k_bin_gemm1<<<NBB + GB, 256, 0, stream>>>(ei, gcur, staged, x, WTg, h1);
    k_bsort    <<<NBUCK, 256, 0, stream>>>(staged, gcur, rowstart, dis, slots,
                                           (__half2*)h1);
    k_agg1     <<<2 * ((Nn + 63) / 64), 256, 0, stream>>>(slots, rowstart, dis,
                                                          (const uint4*)h1, b1, a1);
    k_gemm2    <<<(Nn + 63) / 64, 256, 0, stream>>>(a1, W2T, dis, h2g);
    k_agg2     <<<(Nn + 63) / 64, 256, 0, stream>>>(slots, rowstart, dis,
                                                    (const uint4*)h2g, b2, out);
}